// Round 1
// baseline (309.169 us; speedup 1.0000x reference)
//
#include <hip/hip_runtime.h>
#include <math.h>

constexpr int BN = 8192;   // batch
constexpr int CN = 4096;   // classes
constexpr int NT = 256;    // threads per block (4 waves)

// One block per batch row. Stages x-row and rank-row in LDS, computes:
//   ws[b]      = sum_j log2_pijk  (sc partial, negative)
//   ws[BN + b] = -logp[b, target[b]]  (ce per-row term)
__global__ __launch_bounds__(NT) void sc_row_kernel(
    const float* __restrict__ x,
    const int*   __restrict__ target,
    const int*   __restrict__ distance_rank,
    const int*   __restrict__ k_idx,
    float*       __restrict__ ws)
{
    __shared__ float xs[CN];
    __shared__ int   rk[CN];
    __shared__ float sred[NT / 64];

    const int b    = blockIdx.x;
    const int tid  = threadIdx.x;
    const int lane = tid & 63;
    const int wave = tid >> 6;

    const int t = target[b];
    const float* __restrict__ xrow = x + (size_t)b * CN;
    const int*   __restrict__ drow = distance_rank + (size_t)t * CN;

    // Stage x row + rank row into LDS (vectorized 16B)
    for (int i = tid; i < CN / 4; i += NT) {
        reinterpret_cast<float4*>(xs)[i] = reinterpret_cast<const float4*>(xrow)[i];
        reinterpret_cast<int4*>(rk)[i]   = reinterpret_cast<const int4*>(drow)[i];
    }
    __syncthreads();

    // ---- cross entropy: row max ----
    float m = -__builtin_huge_valf();
    for (int i = tid; i < CN; i += NT) m = fmaxf(m, xs[i]);
    for (int off = 32; off; off >>= 1) m = fmaxf(m, __shfl_down(m, off, 64));
    if (lane == 0) sred[wave] = m;
    __syncthreads();
    m = fmaxf(fmaxf(sred[0], sred[1]), fmaxf(sred[2], sred[3]));
    __syncthreads();

    // ---- sum of exp(x - m) ----
    float s = 0.f;
    for (int i = tid; i < CN; i += NT) s += __expf(xs[i] - m);
    for (int off = 32; off; off >>= 1) s += __shfl_down(s, off, 64);
    if (lane == 0) sred[wave] = s;
    __syncthreads();
    s = sred[0] + sred[1] + sred[2] + sred[3];
    __syncthreads();

    if (tid == 0) ws[BN + b] = __logf(s) + m - xs[t];   // -logp[target]

    // ---- sc term ----
    const float yi        = xs[rk[1]];
    const float inv_alpha = 1.0f / (float)(CN - 1);
    const float e         = -0.5f * (float)CN;          // -(alpha+1)/2
    const int* __restrict__ krow = k_idx + (size_t)b * (CN - 3);

    float acc = 0.f;
    for (int j = tid; j < CN - 3; j += NT) {
        const float yj = xs[rk[2 + j]];
        const int   kk = krow[j];
        const float yk = xs[rk[kk]];
        const float dj = yi - yj;
        const float dk = yi - yk;
        const float la = e * log1pf(dj * dj * inv_alpha);
        const float lb = e * log1pf(dk * dk * inv_alpha);
        const float d  = lb - la;
        // la - logaddexp(la, lb) = -softplus(d), softplus stable form:
        acc -= fmaxf(d, 0.f) + log1pf(__expf(-fabsf(d)));
    }
    acc *= 1.44269504088896340736f;  // /ln(2) -> log2_pijk sum

    for (int off = 32; off; off >>= 1) acc += __shfl_down(acc, off, 64);
    if (lane == 0) sred[wave] = acc;
    __syncthreads();
    if (tid == 0) ws[b] = sred[0] + sred[1] + sred[2] + sred[3];
}

// Deterministic final reduction of the 2*BN partials, double accumulation.
__global__ __launch_bounds__(256) void sc_finalize(
    const float* __restrict__ ws, float* __restrict__ out)
{
    __shared__ double dred[8];
    const int tid  = threadIdx.x;
    const int lane = tid & 63;
    const int wave = tid >> 6;

    double sc = 0.0, ce = 0.0;
    for (int i = tid; i < BN; i += 256) {
        sc += (double)ws[i];
        ce += (double)ws[BN + i];
    }
    for (int off = 32; off; off >>= 1) {
        sc += __shfl_down(sc, off, 64);
        ce += __shfl_down(ce, off, 64);
    }
    if (lane == 0) { dred[wave] = sc; dred[4 + wave] = ce; }
    __syncthreads();
    if (tid == 0) {
        double scs = dred[0] + dred[1] + dred[2] + dred[3];
        double ces = dred[4] + dred[5] + dred[6] + dred[7];
        double ce_mean = ces / (double)BN;
        double sc_val  = -scs / (double)BN / (double)(CN - 1);
        out[0] = (float)(0.6 * ce_mean + 0.4 * sc_val);
    }
}

extern "C" void kernel_launch(void* const* d_in, const int* in_sizes, int n_in,
                              void* d_out, int out_size, void* d_ws, size_t ws_size,
                              hipStream_t stream) {
    const float* x             = (const float*)d_in[0];
    const int*   target        = (const int*)d_in[1];
    const int*   distance_rank = (const int*)d_in[2];
    const int*   k_idx         = (const int*)d_in[3];
    float*       ws            = (float*)d_ws;

    sc_row_kernel<<<BN, NT, 0, stream>>>(x, target, distance_rank, k_idx, ws);
    sc_finalize<<<1, 256, 0, stream>>>(ws, (float*)d_out);
}

// Round 3
// 93.776 us; speedup vs baseline: 3.2969x; 3.2969x over previous
//
#include <hip/hip_runtime.h>
#include <math.h>

constexpr int BN = 8192;   // batch
constexpr int CN = 4096;   // classes
constexpr int NT = 512;    // threads per block (8 waves)
constexpr int NW = NT / 64;

// One block per batch row.
//   ws[b]      = sum_j log2_pijk  (sc partial, negative)
//   ws[BN + b] = -logp[b, target[b]]  (ce per-row term)
__global__ __launch_bounds__(NT) void sc_row_kernel(
    const float* __restrict__ x,
    const int*   __restrict__ target,
    const int*   __restrict__ distance_rank,
    const int*   __restrict__ k_idx,
    float*       __restrict__ ws)
{
    __shared__ float xs[CN];
    __shared__ int   rk[CN];     // later overwritten with y[c] = xs[rk[c]]
    __shared__ float sred[NW];
    float* yf = reinterpret_cast<float*>(rk);

    const int b    = blockIdx.x;
    const int tid  = threadIdx.x;
    const int lane = tid & 63;
    const int wave = tid >> 6;

    const int t = target[b];
    const float* __restrict__ xrow = x + (size_t)b * CN;
    const int*   __restrict__ drow = distance_rank + (size_t)t * CN;

    // Stage x row + rank row into LDS (16B vectorized)
    for (int i = tid; i < CN / 4; i += NT) {
        reinterpret_cast<float4*>(xs)[i] = reinterpret_cast<const float4*>(xrow)[i];
        reinterpret_cast<int4*>(rk)[i]   = reinterpret_cast<const int4*>(drow)[i];
    }
    __syncthreads();

    // Save this thread's rk entries to registers (for the in-place y transform)
    int rkv[CN / NT];
    #pragma unroll
    for (int i = 0; i < CN / NT; ++i) rkv[i] = rk[tid + i * NT];

    // ---- cross entropy: row max ----
    float m = -__builtin_huge_valf();
    for (int i = tid; i < CN; i += NT) m = fmaxf(m, xs[i]);
    for (int off = 32; off; off >>= 1) m = fmaxf(m, __shfl_down(m, off, 64));
    if (lane == 0) sred[wave] = m;
    __syncthreads();
    m = sred[0];
    #pragma unroll
    for (int w = 1; w < NW; ++w) m = fmaxf(m, sred[w]);
    __syncthreads();

    // ---- sum of exp(x - m) ----
    float s = 0.f;
    for (int i = tid; i < CN; i += NT) s += __expf(xs[i] - m);
    for (int off = 32; off; off >>= 1) s += __shfl_down(s, off, 64);
    if (lane == 0) sred[wave] = s;
    __syncthreads();            // also guarantees all rk reads above are done
    s = sred[0];
    #pragma unroll
    for (int w = 1; w < NW; ++w) s += sred[w];

    if (tid == 0) ws[BN + b] = __logf(s) + m - xs[t];   // -logp[target]

    // ---- in-place transform: yf[c] = xs[rk[c]] ----
    #pragma unroll
    for (int i = 0; i < CN / NT; ++i) yf[tid + i * NT] = xs[rkv[i]];
    __syncthreads();

    // ---- sc term, all in log2 space ----
    // la2 = e*(log2(a+dj^2) - log2(a));  D = lb2-la2 = e*(Lk - Lj)
    // log2_pijk = -(max(D,0) + log2(1 + 2^-|D|))
    const float yi    = yf[1];
    const float alpha = (float)(CN - 1);
    const float e     = -0.5f * (float)CN;
    const int* __restrict__ krow = k_idx + (size_t)b * (CN - 3);

    float acc = 0.f;
    for (int j = tid; j < CN - 3; j += NT) {
        const float yj = yf[2 + j];       // contiguous LDS read
        const int   kk = krow[j];         // coalesced global read
        const float yk = yf[kk];          // single random LDS gather
        const float dj = yi - yj;
        const float dk = yi - yk;
        const float Lj = __log2f(fmaf(dj, dj, alpha));
        const float Lk = __log2f(fmaf(dk, dk, alpha));
        const float D  = e * (Lk - Lj);
        acc -= fmaxf(D, 0.f) + __log2f(1.0f + __builtin_amdgcn_exp2f(-fabsf(D)));
    }

    for (int off = 32; off; off >>= 1) acc += __shfl_down(acc, off, 64);
    if (lane == 0) sred[wave] = acc;
    __syncthreads();
    if (tid == 0) {
        float a0 = sred[0];
        #pragma unroll
        for (int w = 1; w < NW; ++w) a0 += sred[w];
        ws[b] = a0;
    }
}

// Deterministic final reduction of the 2*BN partials, double accumulation.
__global__ __launch_bounds__(256) void sc_finalize(
    const float* __restrict__ ws, float* __restrict__ out)
{
    __shared__ double dred[8];
    const int tid  = threadIdx.x;
    const int lane = tid & 63;
    const int wave = tid >> 6;

    double sc = 0.0, ce = 0.0;
    for (int i = tid; i < BN; i += 256) {
        sc += (double)ws[i];
        ce += (double)ws[BN + i];
    }
    for (int off = 32; off; off >>= 1) {
        sc += __shfl_down(sc, off, 64);
        ce += __shfl_down(ce, off, 64);
    }
    if (lane == 0) { dred[wave] = sc; dred[4 + wave] = ce; }
    __syncthreads();
    if (tid == 0) {
        double scs = dred[0] + dred[1] + dred[2] + dred[3];
        double ces = dred[4] + dred[5] + dred[6] + dred[7];
        double ce_mean = ces / (double)BN;
        double sc_val  = -scs / (double)BN / (double)(CN - 1);
        out[0] = (float)(0.6 * ce_mean + 0.4 * sc_val);
    }
}

extern "C" void kernel_launch(void* const* d_in, const int* in_sizes, int n_in,
                              void* d_out, int out_size, void* d_ws, size_t ws_size,
                              hipStream_t stream) {
    const float* x             = (const float*)d_in[0];
    const int*   target        = (const int*)d_in[1];
    const int*   distance_rank = (const int*)d_in[2];
    const int*   k_idx         = (const int*)d_in[3];
    float*       ws            = (float*)d_ws;

    sc_row_kernel<<<BN, NT, 0, stream>>>(x, target, distance_rank, k_idx, ws);
    sc_finalize<<<1, 256, 0, stream>>>(ws, (float*)d_out);
}

// Round 4
// 72.705 us; speedup vs baseline: 4.2524x; 1.2898x over previous
//
#include <hip/hip_runtime.h>
#include <math.h>

constexpr int BN  = 8192;   // batch
constexpr int CN  = 4096;   // classes
constexpr int NT  = 512;    // threads per block (8 waves)
constexpr int NW  = NT / 64;
constexpr int EPT = CN / NT;   // 8 scalar elements per thread
constexpr int V4  = EPT / 4;   // 2 float4 per thread

// One block per batch row.
//   ws[b]      = sum_j log2_pijk  (sc partial, negative)
//   ws[BN + b] = -logp[b, target[b]]  (ce per-row term)
__global__ __launch_bounds__(NT) void sc_row_kernel(
    const float* __restrict__ x,
    const int*   __restrict__ target,
    const int*   __restrict__ distance_rank,
    const int*   __restrict__ k_idx,
    float*       __restrict__ ws)
{
    __shared__ float xs[CN];
    __shared__ float yf[CN];          // yf[c] = xs[rk[c]]
    __shared__ float red_m[NW], red_s[NW], red_a[NW];

    const int b    = blockIdx.x;
    const int tid  = threadIdx.x;
    const int lane = tid & 63;
    const int wave = tid >> 6;

    const int t = target[b];
    const float* __restrict__ xrow = x + (size_t)b * CN;
    const int*   __restrict__ drow = distance_rank + (size_t)t * CN;
    const int*   __restrict__ krow = k_idx + (size_t)b * (CN - 3);

    // ---- prefetch k indices to registers (in flight during everything below)
    int kkv[EPT];
    #pragma unroll
    for (int i = 0; i < EPT; ++i) {
        const int j = tid + i * NT;
        kkv[i] = (j < CN - 3) ? krow[j] : 1;
    }

    // ---- stage x row to LDS via registers; rank row to registers only
    float4 xv[V4];
    int4   rv[V4];
    #pragma unroll
    for (int i = 0; i < V4; ++i) {
        xv[i] = reinterpret_cast<const float4*>(xrow)[tid + i * NT];
        rv[i] = reinterpret_cast<const int4*>(drow)[tid + i * NT];
        reinterpret_cast<float4*>(xs)[tid + i * NT] = xv[i];
    }

    // ---- online softmax on the register copies (no LDS re-read)
    float ml = -__builtin_huge_valf();
    #pragma unroll
    for (int i = 0; i < V4; ++i) {
        ml = fmaxf(ml, fmaxf(fmaxf(xv[i].x, xv[i].y), fmaxf(xv[i].z, xv[i].w)));
    }
    float sl = 0.f;
    #pragma unroll
    for (int i = 0; i < V4; ++i) {
        sl += __expf(xv[i].x - ml) + __expf(xv[i].y - ml)
            + __expf(xv[i].z - ml) + __expf(xv[i].w - ml);
    }
    // wave-level (m,s) pair merge
    #pragma unroll
    for (int off = 32; off; off >>= 1) {
        const float mo = __shfl_down(ml, off, 64);
        const float so = __shfl_down(sl, off, 64);
        const float mn = fmaxf(ml, mo);
        sl = sl * __expf(ml - mn) + so * __expf(mo - mn);
        ml = mn;
    }
    if (lane == 0) { red_m[wave] = ml; red_s[wave] = sl; }

    __syncthreads();   // xs staged + per-wave (m,s) pairs visible

    // cross-wave merge (every thread, redundant but barrier-free)
    float mg = red_m[0];
    #pragma unroll
    for (int w = 1; w < NW; ++w) mg = fmaxf(mg, red_m[w]);
    float sg = 0.f;
    #pragma unroll
    for (int w = 0; w < NW; ++w) sg += red_s[w] * __expf(red_m[w] - mg);

    if (tid == 0) ws[BN + b] = __logf(sg) + mg - xs[t];   // -logp[target]

    // ---- transform: yf[c] = xs[rk[c]] (gather from xs, b128 contiguous write)
    #pragma unroll
    for (int i = 0; i < V4; ++i) {
        float4 yv;
        yv.x = xs[rv[i].x];
        yv.y = xs[rv[i].y];
        yv.z = xs[rv[i].z];
        yv.w = xs[rv[i].w];
        reinterpret_cast<float4*>(yf)[tid + i * NT] = yv;
    }
    __syncthreads();   // yf ready

    // ---- sc term, log2 space:
    // D = e*(log2(a+dk^2) - log2(a+dj^2));  log2_pijk = -(max(D,0)+log2(1+2^-|D|))
    const float yi    = yf[1];
    const float alpha = (float)(CN - 1);
    const float e     = -0.5f * (float)CN;

    float acc = 0.f;
    #pragma unroll
    for (int i = 0; i < EPT; ++i) {
        const int j = tid + i * NT;
        if (j < CN - 3) {
            const float yj = yf[2 + j];      // contiguous LDS read
            const float yk = yf[kkv[i]];     // random LDS gather (idx preloaded)
            const float dj = yi - yj;
            const float dk = yi - yk;
            const float Lj = __log2f(fmaf(dj, dj, alpha));
            const float Lk = __log2f(fmaf(dk, dk, alpha));
            const float D  = e * (Lk - Lj);
            acc -= fmaxf(D, 0.f) + __log2f(1.0f + __builtin_amdgcn_exp2f(-fabsf(D)));
        }
    }

    #pragma unroll
    for (int off = 32; off; off >>= 1) acc += __shfl_down(acc, off, 64);
    if (lane == 0) red_a[wave] = acc;
    __syncthreads();
    if (tid == 0) {
        float a0 = red_a[0];
        #pragma unroll
        for (int w = 1; w < NW; ++w) a0 += red_a[w];
        ws[b] = a0;
    }
}

// Deterministic final reduction of the 2*BN partials, double accumulation.
__global__ __launch_bounds__(256) void sc_finalize(
    const float* __restrict__ ws, float* __restrict__ out)
{
    __shared__ double dred[8];
    const int tid  = threadIdx.x;
    const int lane = tid & 63;
    const int wave = tid >> 6;

    double sc = 0.0, ce = 0.0;
    for (int i = tid; i < BN; i += 256) {
        sc += (double)ws[i];
        ce += (double)ws[BN + i];
    }
    for (int off = 32; off; off >>= 1) {
        sc += __shfl_down(sc, off, 64);
        ce += __shfl_down(ce, off, 64);
    }
    if (lane == 0) { dred[wave] = sc; dred[4 + wave] = ce; }
    __syncthreads();
    if (tid == 0) {
        double scs = dred[0] + dred[1] + dred[2] + dred[3];
        double ces = dred[4] + dred[5] + dred[6] + dred[7];
        double ce_mean = ces / (double)BN;
        double sc_val  = -scs / (double)BN / (double)(CN - 1);
        out[0] = (float)(0.6 * ce_mean + 0.4 * sc_val);
    }
}

extern "C" void kernel_launch(void* const* d_in, const int* in_sizes, int n_in,
                              void* d_out, int out_size, void* d_ws, size_t ws_size,
                              hipStream_t stream) {
    const float* x             = (const float*)d_in[0];
    const int*   target        = (const int*)d_in[1];
    const int*   distance_rank = (const int*)d_in[2];
    const int*   k_idx         = (const int*)d_in[3];
    float*       ws            = (float*)d_ws;

    sc_row_kernel<<<BN, NT, 0, stream>>>(x, target, distance_rank, k_idx, ws);
    sc_finalize<<<1, 256, 0, stream>>>(ws, (float*)d_out);
}